// Round 7
// baseline (243.151 us; speedup 1.0000x reference)
//
#include <hip/hip_runtime.h>

#pragma clang fp contract(off)

#define B_  512
#define N_  16384
#define A_  64
#define SL  8          // slices per batch (K1/K3)
#define EPT 8          // elements per thread (K1/K3)
#define CAP 2048

typedef float  vfloat4 __attribute__((ext_vector_type(4)));   // NT-store-able

// ---------------- K1: pure stream: distances -> packed 16-bit prefixes -----
__global__ __launch_bounds__(256) void k1_dist(
    const float* __restrict__ pos,  const float* __restrict__ mask,
    const float* __restrict__ apos, const float* __restrict__ amask,
    float* __restrict__ centws, unsigned short* __restrict__ ws16)
{
#pragma clang fp contract(off)
    __shared__ float s_c[3];
    const int tid = threadIdx.x;
    const int blk = blockIdx.x;
    const int b = blk >> 3, sl = blk & 7;

    // wave 0: centroid, bit-exact numpy reduction orders
    if (tid < 64) {
        const float* ap = apos  + (size_t)b * (A_ * 3);
        const float* am = amask + (size_t)b * A_;
        float comp = 0.0f, ms = 0.0f;
        if (tid < 3) {                       // axis=-2 sequential accumulate
            comp = ap[tid];
            for (int a = 1; a < A_; ++a) comp += ap[a * 3 + tid];
        }
        if (tid == 3) {                      // numpy pairwise-8 for n=64
            float r0 = am[0], r1 = am[1], r2 = am[2], r3 = am[3];
            float r4 = am[4], r5 = am[5], r6 = am[6], r7 = am[7];
            for (int i = 8; i < A_; i += 8) {
                r0 += am[i + 0]; r1 += am[i + 1]; r2 += am[i + 2]; r3 += am[i + 3];
                r4 += am[i + 4]; r5 += am[i + 5]; r6 += am[i + 6]; r7 += am[i + 7];
            }
            ms = ((r0 + r1) + (r2 + r3)) + ((r4 + r5) + (r6 + r7));
        }
        ms = __shfl(ms, 3, 64);
        if (tid < 3) s_c[tid] = comp / ms;   // correctly-rounded fp32 divide
    }
    __syncthreads();
    if (sl == 0 && tid < 3) centws[b * 4 + tid] = s_c[tid];

    const float cx = s_c[0], cy = s_c[1], cz = s_c[2];
    const int base = b * N_ + sl * 2048 + tid * EPT;
    const float* __restrict__ p = pos  + (size_t)base * 3;
    const float* __restrict__ m = mask + base;

    unsigned bits[EPT];
#pragma unroll
    for (int g = 0; g < 2; ++g) {
        const float4 pa = *(const float4*)(p + g * 12);
        const float4 pb = *(const float4*)(p + g * 12 + 4);
        const float4 pc = *(const float4*)(p + g * 12 + 8);
        const float4 mv = *(const float4*)(m + g * 4);
        const float px[4] = {pa.x, pa.w, pb.z, pc.y};
        const float py[4] = {pa.y, pb.x, pb.w, pc.z};
        const float pz[4] = {pa.z, pb.y, pc.x, pc.w};
        const float mm[4] = {mv.x, mv.y, mv.z, mv.w};
#pragma unroll
        for (int j = 0; j < 4; ++j) {
            float dx = cx - px[j], dy = cy - py[j], dz = cz - pz[j];
            float dx2 = dx * dx, dy2 = dy * dy, dz2 = dz * dz;
            float s = (dx2 + dy2) + dz2;     // numpy last-axis sum order
            s = s + 1e-12f;
            float d = sqrtf(s);              // correctly rounded
            d = d + (1.0f - mm[j]) * 1e10f;
            bits[g * 4 + j] = __float_as_uint(d);   // monotone, d > 0
        }
    }
    uint4 pk;
    pk.x = (bits[0] >> 16) | ((bits[1] >> 16) << 16);
    pk.y = (bits[2] >> 16) | ((bits[3] >> 16) << 16);
    pk.z = (bits[4] >> 16) | ((bits[5] >> 16) << 16);
    pk.w = (bits[6] >> 16) | ((bits[7] >> 16) << 16);
    *(uint4*)(ws16 + base) = pk;             // L2/L3-resident for K2/K3
}

// ---------------- K2: histogram + exact threshold + boundary marking -------
__global__ __launch_bounds__(1024) void k2_select(
    const float* __restrict__ pos, const float* __restrict__ mask,
    const int* __restrict__ topk_ptr, const float* __restrict__ centws,
    unsigned* __restrict__ P16arr, unsigned short* __restrict__ ws16)
{
#pragma clang fp contract(off)
    __shared__ unsigned       hist[2048];
    __shared__ unsigned       hist2[32];
    __shared__ unsigned       cand_bits[CAP];
    __shared__ unsigned short cand_idx[CAP];
    __shared__ float          s_c[3];
    __shared__ unsigned       s_B11, s_cum, s_P16, s_j, s_ncand, s_k;

    const int tid = threadIdx.x;
    const int b   = blockIdx.x;
    hist[tid] = 0u; hist[tid + 1024] = 0u;
    if (tid < 32) hist2[tid] = 0u;
    if (tid < 3)  s_c[tid] = centws[b * 4 + tid];
    if (tid == 0) {
        s_ncand = 0u;
        int kk = *topk_ptr;
        if (kk < 0)  kk = 0;
        if (kk > N_) kk = N_;
        s_k = (unsigned)kk;
    }
    __syncthreads();
    const unsigned k = s_k;
    if (k == 0u) { if (tid == 0) P16arr[b] = 0u; return; }

    // build 2048-bin histogram from prefixes (key = prefix >> 5)
    unsigned short* __restrict__ w16 = ws16 + (size_t)b * N_;
    const uint4* wp = (const uint4*)(w16 + (size_t)tid * 16);
    const uint4 a0 = wp[0];
    const uint4 a1 = wp[1];
    const unsigned pref[16] = {
        a0.x & 0xFFFFu, a0.x >> 16, a0.y & 0xFFFFu, a0.y >> 16,
        a0.z & 0xFFFFu, a0.z >> 16, a0.w & 0xFFFFu, a0.w >> 16,
        a1.x & 0xFFFFu, a1.x >> 16, a1.y & 0xFFFFu, a1.y >> 16,
        a1.z & 0xFFFFu, a1.z >> 16, a1.w & 0xFFFFu, a1.w >> 16 };
#pragma unroll
    for (int x = 0; x < 16; ++x) atomicAdd(&hist[pref[x] >> 5], 1u);
    __syncthreads();

    // level-1 + level-2 scan over the 2048-bin histogram (wave 0)
    if (tid < 64) {
        const uint4* hp = (const uint4*)&hist[tid * 32];
        unsigned ssum = 0;
#pragma unroll
        for (int r = 0; r < 8; ++r) { const uint4 h = hp[r]; ssum += h.x + h.y + h.z + h.w; }
        unsigned incl = ssum;
#pragma unroll
        for (int off = 1; off < 64; off <<= 1) {
            const unsigned v = (unsigned)__shfl_up((int)incl, off, 64);
            if (tid >= off) incl += v;
        }
        const unsigned long long bal = __ballot(incl >= k);
        const int g64 = __ffsll(bal) - 1;
        const unsigned cum64 = (unsigned)__shfl((int)(incl - ssum), g64, 64);
        const unsigned h2 = (tid < 32) ? hist[g64 * 32 + tid] : 0u;
        unsigned incl2 = h2;
#pragma unroll
        for (int off = 1; off < 64; off <<= 1) {
            const unsigned v = (unsigned)__shfl_up((int)incl2, off, 64);
            if (tid >= off) incl2 += v;
        }
        const unsigned long long bal2 = __ballot(tid < 32 && (cum64 + incl2 >= k));
        const int sb = __ffsll(bal2) - 1;
        const unsigned cum = cum64 + (unsigned)__shfl((int)(incl2 - h2), sb, 64);
        if (tid == 0) { s_B11 = (unsigned)(g64 * 32 + sb); s_cum = cum; }
    }
    __syncthreads();
    const unsigned B11 = s_B11;

    // refine low 5 bits of the prefix
#pragma unroll
    for (int x = 0; x < 16; ++x)
        if ((pref[x] >> 5) == B11) atomicAdd(&hist2[pref[x] & 31u], 1u);
    __syncthreads();
    if (tid < 64) {
        const unsigned h = (tid < 32) ? hist2[tid] : 0u;
        unsigned incl = h;
#pragma unroll
        for (int off = 1; off < 64; off <<= 1) {
            const unsigned v = (unsigned)__shfl_up((int)incl, off, 64);
            if (tid >= off) incl += v;
        }
        const unsigned cum0 = s_cum;
        const unsigned long long bal = __ballot(tid < 32 && (cum0 + incl >= k));
        const int sb = __ffsll(bal) - 1;
        const unsigned cumx = cum0 + (unsigned)__shfl((int)(incl - h), sb, 64);
        if (tid == 0) { s_P16 = (B11 << 5) | (unsigned)sb; s_j = k - cumx; }
    }
    __syncthreads();
    const unsigned P16 = s_P16, j = s_j;

    // gather ==P16 candidates, recompute full bits (bit-exact, L3-hot pos)
    const float cx = s_c[0], cy = s_c[1], cz = s_c[2];
    const float* __restrict__ p = pos  + (size_t)b * N_ * 3;
    const float* __restrict__ m = mask + (size_t)b * N_;
#pragma unroll
    for (int x = 0; x < 16; ++x) {
        if (pref[x] == P16) {
            const unsigned w = atomicAdd(&s_ncand, 1u);
            if (w < CAP) {
                const int i = tid * 16 + x;
                float dx = cx - p[i * 3], dy = cy - p[i * 3 + 1], dz = cz - p[i * 3 + 2];
                float dx2 = dx * dx, dy2 = dy * dy, dz2 = dz * dz;
                float s = (dx2 + dy2) + dz2;
                s = s + 1e-12f;
                float d = sqrtf(s);
                d = d + (1.0f - m[i]) * 1e10f;
                cand_bits[w] = __float_as_uint(d);
                cand_idx[w]  = (unsigned short)i;
            }
        }
    }
    __syncthreads();

    // rank candidates (tie -> lowest index); mark rank<j in ws16
    const unsigned c = min(s_ncand, (unsigned)CAP);
    for (unsigned t = tid; t < c; t += 1024) {
        const unsigned bt = cand_bits[t];
        const unsigned it = cand_idx[t];
        unsigned rank = 0;
        for (unsigned u = 0; u < c; ++u) {
            const unsigned bu = cand_bits[u];
            rank += (bu < bt) || (bu == bt && (unsigned)cand_idx[u] < it);
        }
        if (rank < j) w16[it] = 0;   // 0 < P16 always (d >= 1e-6)
    }
    if (tid == 0) P16arr[b] = P16;
}

// ---------------- K3: pure stream: prefixes + mask -> both outputs ---------
__global__ __launch_bounds__(256) void k3_write(
    const float* __restrict__ mask, const unsigned* __restrict__ P16arr,
    const unsigned short* __restrict__ ws16,
    float* __restrict__ out0, float* __restrict__ out1)
{
    const int tid = threadIdx.x;
    const int blk = blockIdx.x;
    const int b = blk >> 3, sl = blk & 7;
    const int base = b * N_ + sl * 2048 + tid * EPT;
    const unsigned P16 = P16arr[b];

    const uint4  pk = *(const uint4*)(ws16 + base);
    const float4 m0 = *(const float4*)(mask + base);
    const float4 m1 = *(const float4*)(mask + base + 4);
    const unsigned pre[8] = {pk.x & 0xFFFFu, pk.x >> 16, pk.y & 0xFFFFu, pk.y >> 16,
                             pk.z & 0xFFFFu, pk.z >> 16, pk.w & 0xFFFFu, pk.w >> 16};
    const float mm[8] = {m0.x, m0.y, m0.z, m0.w, m1.x, m1.y, m1.z, m1.w};

    float v0[8], v1[8];
#pragma unroll
    for (int x = 0; x < 8; ++x) {
        const bool sel = pre[x] < P16;
        v0[x] = sel ? 0.0f  : mm[x];
        v1[x] = sel ? 32.0f : (1.0f - mm[x]);
    }
    const vfloat4 o0a = {v0[0], v0[1], v0[2], v0[3]};
    const vfloat4 o0b = {v0[4], v0[5], v0[6], v0[7]};
    const vfloat4 o1a = {v1[0], v1[1], v1[2], v1[3]};
    const vfloat4 o1b = {v1[4], v1[5], v1[6], v1[7]};
    __builtin_nontemporal_store(o0a, (vfloat4*)(out0 + base));
    __builtin_nontemporal_store(o0b, (vfloat4*)(out0 + base + 4));
    __builtin_nontemporal_store(o1a, (vfloat4*)(out1 + base));
    __builtin_nontemporal_store(o1b, (vfloat4*)(out1 + base + 4));
}

extern "C" void kernel_launch(void* const* d_in, const int* in_sizes, int n_in,
                              void* d_out, int out_size, void* d_ws, size_t ws_size,
                              hipStream_t stream) {
    const float* pos   = (const float*)d_in[0];   // [B,N,3]
    const float* rmask = (const float*)d_in[1];   // [B,N]
    const float* apos  = (const float*)d_in[2];   // [B,A,3]
    const float* amask = (const float*)d_in[3];   // [B,A]
    // d_in[4] = max_p (unused by the reference outputs)
    const int*   topk  = (const int*)d_in[5];

    float* out0 = (float*)d_out;
    float* out1 = out0 + (size_t)B_ * N_;

    char* ws = (char*)d_ws;
    float*          centws = (float*)ws;                       // 8 KB
    unsigned*       P16arr = (unsigned*)(ws + 8192);           // 2 KB
    unsigned short* ws16   = (unsigned short*)(ws + 16384);    // 16 MB

    k1_dist  <<<B_ * SL, 256,  0, stream>>>(pos, rmask, apos, amask, centws, ws16);
    k2_select<<<B_,      1024, 0, stream>>>(pos, rmask, topk, centws, P16arr, ws16);
    k3_write <<<B_ * SL, 256,  0, stream>>>(rmask, P16arr, ws16, out0, out1);
}